// Round 3
// baseline (3753.995 us; speedup 1.0000x reference)
//
#include <hip/hip_runtime.h>
#include <hip/hip_bf16.h>

#define TT    1024   // time steps (32x32 raster)
#define KPAD  1088   // 64 (x padded from 48) + 512 (prev2) + 512 (h)
#define LSTR  520    // LDS stage row stride in shorts (512 + 8): 2-way banks (free)
#define NSLOT 48     // ring slots (need > 32 + skew margin)

typedef __attribute__((ext_vector_type(8))) short short8;
typedef __attribute__((ext_vector_type(4))) float floatx4;
typedef __attribute__((ext_vector_type(4))) unsigned int uintx4;
using bf16 = __hip_bfloat16;
typedef unsigned long long ull;

__device__ __forceinline__ float frcp(float x) { return __builtin_amdgcn_rcpf(x); }
__device__ __forceinline__ float fsig(float x) { return frcp(1.f + __expf(-x)); }
__device__ __forceinline__ float ftanh(float x) {
    float e = __expf(2.f * fminf(fmaxf(x, -15.f), 15.f));
    return (e - 1.f) * frcp(e + 1.f);
}

// 16B coherence-point load (sc0 sc1 bypass). Returned data is validated via
// embedded per-8B tags, so no cross-address ordering is required.
__device__ __forceinline__ uintx4 sc_load16u(const void* p) {
    uintx4 v;
    asm volatile("global_load_dwordx4 %0, %1, off sc0 sc1" : "=v"(v) : "v"(p) : "memory");
    return v;
}
__device__ __forceinline__ void wait_vm0() {
    asm volatile("s_waitcnt vmcnt(0)" ::: "memory");
    __builtin_amdgcn_sched_barrier(0);   // rule #18
}

// Build combined bf16 weight matrix Wc[row][k], k: [0,48)=W_ih x-part, [48,64)=0,
// [64,576)=W_ih prev2-part, [576,1088)=W_hh. Also bias = b_ih + b_hh (fp32).
__global__ void prep_wb(const float* __restrict__ Wih, const float* __restrict__ Whh,
                        const float* __restrict__ bih, const float* __restrict__ bhh,
                        bf16* __restrict__ Wc, float* __restrict__ bias) {
    int idx = blockIdx.x * 256 + threadIdx.x;
    int total = 2048 * KPAD;
    if (idx < total) {
        int row = idx / KPAD;
        int k = idx - row * KPAD;
        float v = 0.f;
        if (k < 48)       v = Wih[row * 560 + k];
        else if (k < 64)  v = 0.f;
        else if (k < 576) v = Wih[row * 560 + 48 + (k - 64)];
        else              v = Whh[row * 512 + (k - 576)];
        Wc[idx] = __float2bfloat16(v);
    }
    if (idx < 2048) bias[idx] = bih[idx] + bhh[idx];
}

// Extract patches: xs[t][b][kk] (kk = c*16 + py*4 + px, padded 48->64), bf16.
__global__ void prep_x(const float* __restrict__ batch, bf16* __restrict__ xs) {
    int idx = blockIdx.x * 256 + threadIdx.x;   // exactly 1024*64*64 threads
    int kk = idx & 63;
    int b  = (idx >> 6) & 63;
    int t  = idx >> 12;
    float v = 0.f;
    if (kk < 48) {
        int c = kk >> 4, py = (kk >> 2) & 3, px = kk & 3;
        int i = t >> 5, j = t & 31;
        v = batch[((b * 3 + c) * 128 + (i * 4 + py)) * 128 + (j * 4 + px)];
    }
    xs[idx] = __float2bfloat16(v);
}

// Persistent 2D-LSTM. 64 WGs x 512 threads = 4 batch-groups x 16 cell-chunk WGs.
// Wave w: gate (w&3), cell-sub (w>>2); 16 cells x 16 batches per gate per step.
//
// R3 exchange redesign — self-validating packets (NO flags, NO store-ack):
//  - ring element = 8B packet {4B data (2 bf16 cells), 4B tag = step+1}.
//    8B atomic store => tag and data are single-copy atomic together: a
//    consumer that sees tag==expected provably sees the data. Immune to
//    fabric reordering; producer never waits (no vmcnt ack, no flag).
//  - ring row (slot, batch) = 256 packets = 2KB (512 cells).
//  - consumers poll-load the data itself (4 dwordx4 per wave, coalesced),
//    issued BEFORE Phase A so first-probe latency hides under MFMAs;
//    validate 8 tags in regs, reload until valid, strip tags, write LDS.
//  - prev2 identical (tag t-30, written 31 steps ago: first probe passes).
//  - 2 barriers/step (B1 stage-ready, B2 gsm). Hazards (rendezvous logic):
//    hbuf writes (t) are after B2(t-1) in writer program order; Phase-B(t-1)
//    readers are before B2(t-1) => separated. p2buf[par] writes (t) vs
//    readers (t+1): separated by B1(t). gsm writes (t) vs cell reads (t-1):
//    separated by B1(t) (cell waves finish (t-1) before arriving at B1(t)).
//  - ring reuse: writer at t hits slot (t+32)%48; that slot's old content
//    h(t-16) was last read (as prev2) at step t-16+32-48+... >= 14 steps
//    earlier than any reader; group skew is <=~2 steps (step t requires all
//    WGs' h(t-1)). Safe margin >10 steps.
__launch_bounds__(512, 1)
__global__ void lstm_persist(const bf16* __restrict__ Wc, const float* __restrict__ bias,
                             const bf16* __restrict__ xs, bf16* __restrict__ ring,
                             float* __restrict__ out)
{
    __shared__ float gsm[4][16][36];       // [gate][batch][cell-in-32]
    __shared__ short p2buf[2][16 * LSTR];  // prev2 double buffer
    __shared__ short hbuf[16 * LSTR];      // h(t-1) stage

    const int wg   = blockIdx.x;
    const int bg   = wg & 3;           // batch group 0..3
    const int wgc  = wg >> 2;          // cell chunk 0..15 (32 cells each)
    const int tid  = threadIdx.x;
    const int w    = tid >> 6;         // wave 0..7
    const int lane = tid & 63;
    const int mrow = lane & 15;        // A: batch-in-16; B/D: cell-in-16
    const int quad = lane >> 4;
    const int gate = w & 3;
    const int sc   = w >> 2;           // cell-sub 0..1

    // ---- weights -> VGPRs, pinned ----
    const int grow = gate * 512 + wgc * 32 + sc * 16 + mrow;
    short8 wf[34];
    {
        const short* wsrc = (const short*)Wc + (size_t)grow * KPAD + quad * 8;
        #pragma unroll
        for (int i = 0; i < 34; ++i) wf[i] = *(const short8*)(wsrc + i * 32);
        #pragma unroll
        for (int i = 0; i < 34; ++i) { asm volatile("" : "+v"(wf[i])); }
    }
    const float bias_r = bias[grow];

    char* ringB = (char*)ring;

    // staging role: wave w stages batch rows 2w, 2w+1; lane covers 32B of a
    // 2KB packet-row (4 packets = cells 8*lane..+8).
    const int r0 = 2 * w;
    // c-state: waves 0,1; lane l owns batch 8w+(l>>3), cells (l&7)*4 .. +4
    floatx4 cst = {0.f, 0.f, 0.f, 0.f};

    // ---- prologue: p2buf[0] = zeros (prev2 for t=0 is h(-32) = 0) ----
    {
        short8 z = {0, 0, 0, 0, 0, 0, 0, 0};
        *(short8*)&p2buf[0][(r0 + 0) * LSTR + lane * 8] = z;
        *(short8*)&p2buf[0][(r0 + 1) * LSTR + lane * 8] = z;
    }
    __syncthreads();

    int sl_h = 31, sl_p = 1, sl_w = 32;   // (t+31)%48, (t+1)%48, (t+32)%48

    for (int t = 0; t < TT; ++t) {
        // ---- (1) issue probes: h(t-1) + prev2-for-(t+1); latency hides under Phase A ----
        const char* hgp = ringB + ((size_t)(sl_h * 64 + bg * 16 + r0)) * 2048 + lane * 32;
        uintx4 a0 = sc_load16u(hgp),        a1 = sc_load16u(hgp + 16);
        uintx4 a2 = sc_load16u(hgp + 2048), a3 = sc_load16u(hgp + 2064);
        const char* pgp = ringB + ((size_t)(sl_p * 64 + bg * 16 + r0)) * 2048 + lane * 32;
        uintx4 b0 = sc_load16u(pgp),        b1 = sc_load16u(pgp + 16);
        uintx4 b2 = sc_load16u(pgp + 2048), b3 = sc_load16u(pgp + 2064);

        // ---- (2) Phase A: x + prev2 partial gates (independent of h(t-1)) ----
        floatx4 acc[4];
        #pragma unroll
        for (int r = 0; r < 4; ++r) acc[r] = (floatx4){0.f, 0.f, 0.f, 0.f};
        {
            const short* xrow = (const short*)xs + ((size_t)t * 64 + bg * 16 + mrow) * 64 + quad * 8;
            short8 xa0 = *(const short8*)(xrow);
            short8 xa1 = *(const short8*)(xrow + 32);
            acc[0] = __builtin_amdgcn_mfma_f32_16x16x32_bf16(xa0, wf[0], acc[0], 0, 0, 0);
            acc[1] = __builtin_amdgcn_mfma_f32_16x16x32_bf16(xa1, wf[1], acc[1], 0, 0, 0);
            const short* pb = &p2buf[t & 1][mrow * LSTR + quad * 8];
            #pragma unroll
            for (int i = 0; i < 16; ++i) {
                short8 a = *(const short8*)(pb + i * 32);
                acc[(2 + i) & 3] = __builtin_amdgcn_mfma_f32_16x16x32_bf16(a, wf[2 + i], acc[(2 + i) & 3], 0, 0, 0);
            }
        }

        // ---- (3) validate prev2 (written ~31 steps ago: first probe passes) ----
        wait_vm0();
        {
            const unsigned expp = (t >= 31) ? (unsigned)(t - 30) : 0u;
            for (;;) {
                unsigned m = (b0.y ^ expp) | (b0.w ^ expp) | (b1.y ^ expp) | (b1.w ^ expp)
                           | (b2.y ^ expp) | (b2.w ^ expp) | (b3.y ^ expp) | (b3.w ^ expp);
                if (!__any((int)m)) break;
                b0 = sc_load16u(pgp);        b1 = sc_load16u(pgp + 16);
                b2 = sc_load16u(pgp + 2048); b3 = sc_load16u(pgp + 2064);
                wait_vm0();
            }
        }
        // ---- (4) validate h(t-1): the hot spin ----
        {
            const unsigned exph = (unsigned)t;
            for (;;) {
                unsigned m = (a0.y ^ exph) | (a0.w ^ exph) | (a1.y ^ exph) | (a1.w ^ exph)
                           | (a2.y ^ exph) | (a2.w ^ exph) | (a3.y ^ exph) | (a3.w ^ exph);
                if (!__any((int)m)) break;
                a0 = sc_load16u(hgp);        a1 = sc_load16u(hgp + 16);
                a2 = sc_load16u(hgp + 2048); a3 = sc_load16u(hgp + 2064);
                wait_vm0();
            }
        }

        // ---- (5) strip tags, write LDS stages ----
        {
            uintx4 h0 = {a0.x, a0.z, a1.x, a1.z};
            uintx4 h1 = {a2.x, a2.z, a3.x, a3.z};
            *(uintx4*)&hbuf[(r0 + 0) * LSTR + lane * 8] = h0;
            *(uintx4*)&hbuf[(r0 + 1) * LSTR + lane * 8] = h1;
            uintx4 p0 = {b0.x, b0.z, b1.x, b1.z};
            uintx4 p1 = {b2.x, b2.z, b3.x, b3.z};
            short* pd = &p2buf[(t + 1) & 1][0];
            *(uintx4*)&pd[(r0 + 0) * LSTR + lane * 8] = p0;
            *(uintx4*)&pd[(r0 + 1) * LSTR + lane * 8] = p1;
        }
        __syncthreads();   // B1: hbuf/p2buf visible

        // ---- (6) Phase B: h(t-1) MFMAs ----
        {
            const short* hbp = &hbuf[mrow * LSTR + quad * 8];
            #pragma unroll
            for (int i = 0; i < 16; ++i) {
                short8 a = *(const short8*)(hbp + i * 32);
                acc[(18 + i) & 3] = __builtin_amdgcn_mfma_f32_16x16x32_bf16(a, wf[18 + i], acc[(18 + i) & 3], 0, 0, 0);
            }
        }
        floatx4 s = acc[0] + acc[1] + acc[2] + acc[3];
        #pragma unroll
        for (int r = 0; r < 4; ++r) gsm[gate][quad * 4 + r][sc * 16 + mrow] = s[r] + bias_r;
        __syncthreads();   // B2: gsm visible to cell waves

        // ---- (7) cell phase: waves 0,1 (4 cells/lane); fire-and-forget stores ----
        if (w < 2) {
            const int b16 = 8 * w + (lane >> 3);    // batch in 16
            const int cj  = (lane & 7) * 4;         // first cell of 4 (in 32)
            floatx4 gi = *(const floatx4*)&gsm[0][b16][cj];
            floatx4 gf = *(const floatx4*)&gsm[1][b16][cj];
            floatx4 gg = *(const floatx4*)&gsm[2][b16][cj];
            floatx4 go = *(const floatx4*)&gsm[3][b16][cj];
            floatx4 hh;
            unsigned short hu[4];
            #pragma unroll
            for (int k = 0; k < 4; ++k) {
                float c = fsig(gf[k]) * cst[k] + fsig(gi[k]) * ftanh(gg[k]);
                cst[k] = c;
                float h = fsig(go[k]) * ftanh(c);
                hh[k] = h;
                union { bf16 b; unsigned short u; } cv;
                cv.b = __float2bfloat16(h);
                hu[k] = cv.u;
            }
            unsigned d01 = (unsigned)hu[0] | ((unsigned)hu[1] << 16);
            unsigned d23 = (unsigned)hu[2] | ((unsigned)hu[3] << 16);
            ull tg = ((ull)(unsigned)(t + 1)) << 32;
            ull* wp = (ull*)(ringB + ((size_t)(sl_w * 64 + bg * 16 + b16)) * 2048
                             + ((size_t)(wgc * 16 + (lane & 7) * 2)) * 8);
            __hip_atomic_store(wp,     (ull)d01 | tg, __ATOMIC_RELAXED, __HIP_MEMORY_SCOPE_AGENT);
            __hip_atomic_store(wp + 1, (ull)d23 | tg, __ATOMIC_RELAXED, __HIP_MEMORY_SCOPE_AGENT);
            // out store: fire-and-forget
            *(floatx4*)(out + (size_t)(bg * 16 + b16) * TT * 512 + (size_t)t * 512 + wgc * 32 + cj) = hh;
        }
        // no trailing barrier: waves 2..7 run ahead into (1)/(2) of t+1.

        sl_h = (sl_h + 1 == NSLOT) ? 0 : sl_h + 1;
        sl_p = (sl_p + 1 == NSLOT) ? 0 : sl_p + 1;
        sl_w = (sl_w + 1 == NSLOT) ? 0 : sl_w + 1;
    }
}

extern "C" void kernel_launch(void* const* d_in, const int* in_sizes, int n_in,
                              void* d_out, int out_size, void* d_ws, size_t ws_size,
                              hipStream_t stream) {
    const float* batch = (const float*)d_in[0];
    const float* Wih   = (const float*)d_in[1];
    const float* Whh   = (const float*)d_in[2];
    const float* bih   = (const float*)d_in[3];
    const float* bhh   = (const float*)d_in[4];
    float* out = (float*)d_out;

    char* p = (char*)d_ws;
    bf16*  Wc     = (bf16*)p;     p += (size_t)2048 * KPAD * 2;            // 4,456,448
    float* bias   = (float*)p;    p += (size_t)2048 * 4;                   // 8,192
    bf16*  xs     = (bf16*)p;     p += (size_t)TT * 64 * 64 * 2;           // 8,388,608
    bf16*  ring   = (bf16*)p;     p += (size_t)NSLOT * 64 * 2048;          // 6,291,456 (packet ring)

    // zero ring slots 0..31: prev2 zeros (tag 0) for t<31 and h(-1) at slot 31
    hipMemsetAsync(ring, 0, (size_t)32 * 64 * 2048, stream);

    prep_wb<<<(2048 * KPAD + 255) / 256, 256, 0, stream>>>(Wih, Whh, bih, bhh, Wc, bias);
    prep_x<<<(TT * 64 * 64) / 256, 256, 0, stream>>>(batch, xs);

    lstm_persist<<<64, 512, 0, stream>>>(Wc, bias, xs, ring, out);
}

// Round 4
// 3272.305 us; speedup vs baseline: 1.1472x; 1.1472x over previous
//
#include <hip/hip_runtime.h>
#include <hip/hip_bf16.h>

#define TT   1024    // time steps (32x32 raster)
#define KPAD 1088    // 64 (x padded from 48) + 512 (prev2) + 512 (h)
#define LSTR 520     // LDS stage row stride in shorts (512 + 8)

typedef __attribute__((ext_vector_type(8))) short short8;
typedef __attribute__((ext_vector_type(4))) float floatx4;
using bf16 = __hip_bfloat16;

__device__ __forceinline__ float frcp(float x) { return __builtin_amdgcn_rcpf(x); }
__device__ __forceinline__ float fsig(float x) { return frcp(1.f + __expf(-x)); }
__device__ __forceinline__ float ftanh(float x) {
    float e = __expf(2.f * fminf(fmaxf(x, -15.f), 15.f));
    return (e - 1.f) * frcp(e + 1.f);
}

// 16B coherence-point load (sc0 sc1). Data quiescent once its flag is seen.
__device__ __forceinline__ short8 sc_load16(const short* p) {
    short8 v;
    asm volatile("global_load_dwordx4 %0, %1, off sc0 sc1" : "=v"(v) : "v"(p) : "memory");
    return v;
}
__device__ __forceinline__ void wait_vm0() {
    asm volatile("s_waitcnt vmcnt(0)" ::: "memory");
    __builtin_amdgcn_sched_barrier(0);   // rule #18
}

// Build combined bf16 weight matrix Wc[row][k], k: [0,48)=W_ih x-part, [48,64)=0,
// [64,576)=W_ih prev2-part, [576,1088)=W_hh. Also bias = b_ih + b_hh (fp32).
__global__ void prep_wb(const float* __restrict__ Wih, const float* __restrict__ Whh,
                        const float* __restrict__ bih, const float* __restrict__ bhh,
                        bf16* __restrict__ Wc, float* __restrict__ bias) {
    int idx = blockIdx.x * 256 + threadIdx.x;
    int total = 2048 * KPAD;
    if (idx < total) {
        int row = idx / KPAD;
        int k = idx - row * KPAD;
        float v = 0.f;
        if (k < 48)       v = Wih[row * 560 + k];
        else if (k < 64)  v = 0.f;
        else if (k < 576) v = Wih[row * 560 + 48 + (k - 64)];
        else              v = Whh[row * 512 + (k - 576)];
        Wc[idx] = __float2bfloat16(v);
    }
    if (idx < 2048) bias[idx] = bih[idx] + bhh[idx];
}

// Extract patches: xs[t][b][kk] (kk = c*16 + py*4 + px, padded 48->64), bf16.
__global__ void prep_x(const float* __restrict__ batch, bf16* __restrict__ xs) {
    int idx = blockIdx.x * 256 + threadIdx.x;   // exactly 1024*64*64 threads
    int kk = idx & 63;
    int b  = (idx >> 6) & 63;
    int t  = idx >> 12;
    float v = 0.f;
    if (kk < 48) {
        int c = kk >> 4, py = (kk >> 2) & 3, px = kk & 3;
        int i = t >> 5, j = t & 31;
        v = batch[((b * 3 + c) * 128 + (i * 4 + py)) * 128 + (j * 4 + px)];
    }
    xs[idx] = __float2bfloat16(v);
}

// Persistent 2D-LSTM. 64 WGs x 256 threads = 4 batch-groups x 16 cell-chunk WGs.
// FAT WAVES: 4 waves/WG, wave w = gate w, 32 gate-rows per wave (two 16-col
// MFMA B-sets). One LDS A-frag read feeds TWO MFMAs -> LDS read traffic
// halved vs the 8-wave version (the phase-B LDS stream was on the critical
// path after B1). Weights: 68 short8 frags (272 VGPR) pinned; 1 wave/SIMD.
//
// Exchange protocol identical to the proven R2 skeleton:
//  - per-cell-wave flag (plain agent atomic store, monotonic step counter),
//    producer: h-store -> s_waitcnt vmcnt(0) -> flag.
//  - wave 3 polls all 32 group flags (8B stride, 4 cache lines; 2-deep
//    pipelined poll with counted vmcnt(1)), barrier releases the WG.
//  - after release: issue h sc-loads, run x-MFMAs under the load latency,
//    drain, stage to LDS, B1, phase B, B2, cell.
// Hazards (3 barriers/step: B0 release, B1 stage, B2 gsm):
//  - hbuf writes (t) vs phase-B reads (t-1): separated by B0(t) arrival
//    (arrival implies B2(t-1) passed and phase-B reads done).
//  - p2buf[par] writes (t) vs reads (t+1): separated by B1(t).
//  - gsm writes (t) vs cell reads (t-1): separated by B1(t).
__launch_bounds__(256, 1)
__global__ void lstm_persist(const bf16* __restrict__ Wc, const float* __restrict__ bias,
                             const bf16* __restrict__ xs, bf16* __restrict__ ring,
                             float* __restrict__ out, unsigned* __restrict__ flags)
{
    __shared__ float gsm[4][16][36];       // [gate][batch][cell-in-32]
    __shared__ short p2buf[2][16 * LSTR];  // prev2 double buffer
    __shared__ short hbuf[16 * LSTR];      // h(t-1) stage

    const int wg   = blockIdx.x;
    const int bg   = wg & 3;           // batch group 0..3
    const int wgc  = wg >> 2;          // cell chunk 0..15 (32 cells each)
    const int tid  = threadIdx.x;
    const int w    = tid >> 6;         // wave 0..3 == gate
    const int lane = tid & 63;
    const int mrow = lane & 15;        // A: batch-in-16; B/D: cell-in-16
    const int quad = lane >> 4;

    // ---- weights -> VGPRs (two 16-col sets), pinned ----
    const int growA = w * 512 + wgc * 32 + mrow;        // cells 0..15 of chunk
    const int growB = growA + 16;                       // cells 16..31
    short8 wfA[34], wfB[34];
    {
        const short* wsA = (const short*)Wc + (size_t)growA * KPAD + quad * 8;
        const short* wsB = (const short*)Wc + (size_t)growB * KPAD + quad * 8;
        #pragma unroll
        for (int i = 0; i < 34; ++i) { wfA[i] = *(const short8*)(wsA + i * 32);
                                       wfB[i] = *(const short8*)(wsB + i * 32); }
        #pragma unroll
        for (int i = 0; i < 34; ++i) { asm volatile("" : "+v"(wfA[i]));
                                       asm volatile("" : "+v"(wfB[i])); }
    }
    const float biasA = bias[growA];
    const float biasB = bias[growB];

    unsigned* gflags = flags + bg * 64;    // 32 flags x 8B stride = 256B/group
    const short* ringS = (const short*)ring;

    // staging role: wave w stages batch rows 4w..4w+3; lane = 16B chunk of row.
    const int r0 = 4 * w;
    // c-state: waves 0,1; lane owns batch 8w+(lane>>3), cells (lane&7)*4..+4
    floatx4 cst = {0.f, 0.f, 0.f, 0.f};

    // ---- prologue: p2buf[0] = zeros (prev2 for t=0 is h(-32) = 0) ----
    {
        short8 z = {0, 0, 0, 0, 0, 0, 0, 0};
        #pragma unroll
        for (int j = 0; j < 4; ++j) *(short8*)&p2buf[0][(r0 + j) * LSTR + lane * 8] = z;
    }
    __syncthreads();

    for (int t = 0; t < TT; ++t) {
        // ---- (a0) prefetch prev2 for t+1 (written >=31 steps ago; off critical path) ----
        short8 pv0, pv1, pv2, pv3;
        {
            const short* p2 = ringS + ((size_t)(((t + 1) & 63) * 64 + bg * 16 + r0)) * 512 + lane * 8;
            pv0 = sc_load16(p2);        pv1 = sc_load16(p2 + 512);
            pv2 = sc_load16(p2 + 1024); pv3 = sc_load16(p2 + 1536);
        }
        // x operands -> regs now (normal cached loads); MFMAs deferred to (cx)
        short8 xa0, xa1;
        {
            const short* xrow = (const short*)xs + ((size_t)t * 64 + bg * 16 + mrow) * 64 + quad * 8;
            xa0 = *(const short8*)(xrow);
            xa1 = *(const short8*)(xrow + 32);
            asm volatile("" : "+v"(xa0), "+v"(xa1));
        }

        // ---- (a) Phase A: prev2 partial gates (independent of h(t-1)) ----
        floatx4 accA[4], accB[4];
        #pragma unroll
        for (int r = 0; r < 4; ++r) { accA[r] = (floatx4){0.f, 0.f, 0.f, 0.f};
                                      accB[r] = (floatx4){0.f, 0.f, 0.f, 0.f}; }
        {
            const short* pb = &p2buf[t & 1][mrow * LSTR + quad * 8];
            #pragma unroll
            for (int i = 0; i < 16; ++i) {
                short8 a = *(const short8*)(pb + i * 32);
                accA[(2 + i) & 3] = __builtin_amdgcn_mfma_f32_16x16x32_bf16(a, wfA[2 + i], accA[(2 + i) & 3], 0, 0, 0);
                accB[(2 + i) & 3] = __builtin_amdgcn_mfma_f32_16x16x32_bf16(a, wfB[2 + i], accB[(2 + i) & 3], 0, 0, 0);
            }
        }

        // ---- (b) B0: wave 3 polls 32 flags (2-deep pipelined); barrier releases ----
        if (t) {
            if (w == 3) {
                const unsigned tgt = (unsigned)t;
                const unsigned* fp = gflags + (lane & 31) * 2;
                unsigned va, vb;
                asm volatile("global_load_dword %0, %1, off sc0 sc1" : "=v"(va) : "v"(fp) : "memory");
                asm volatile("global_load_dword %0, %1, off sc0 sc1" : "=v"(vb) : "v"(fp) : "memory");
                for (;;) {
                    asm volatile("s_waitcnt vmcnt(1)" ::: "memory");
                    __builtin_amdgcn_sched_barrier(0);
                    if (!__any((int)(va < tgt))) break;
                    asm volatile("global_load_dword %0, %1, off sc0 sc1" : "=v"(va) : "v"(fp) : "memory");
                    asm volatile("s_waitcnt vmcnt(1)" ::: "memory");
                    __builtin_amdgcn_sched_barrier(0);
                    if (!__any((int)(vb < tgt))) break;
                    asm volatile("global_load_dword %0, %1, off sc0 sc1" : "=v"(vb) : "v"(fp) : "memory");
                }
                // drain dangling poll load (and this wave's prefetches)
                wait_vm0();
            }
            __syncthreads();
        }

        // ---- (c) issue coherence-point h(t-1) loads (4 coalesced 1KB wave-loads) ----
        short8 hv0, hv1, hv2, hv3;
        {
            const short* hb = ringS + ((size_t)(((t + 31) & 63) * 64 + bg * 16 + r0)) * 512 + lane * 8;
            hv0 = sc_load16(hb);        hv1 = sc_load16(hb + 512);
            hv2 = sc_load16(hb + 1024); hv3 = sc_load16(hb + 1536);
        }
        // ---- (cx) x MFMAs execute under the h-load latency ----
        accA[0] = __builtin_amdgcn_mfma_f32_16x16x32_bf16(xa0, wfA[0], accA[0], 0, 0, 0);
        accA[1] = __builtin_amdgcn_mfma_f32_16x16x32_bf16(xa1, wfA[1], accA[1], 0, 0, 0);
        accB[0] = __builtin_amdgcn_mfma_f32_16x16x32_bf16(xa0, wfB[0], accB[0], 0, 0, 0);
        accB[1] = __builtin_amdgcn_mfma_f32_16x16x32_bf16(xa1, wfB[1], accB[1], 0, 0, 0);

        // ---- (d) drain, write LDS stages ----
        wait_vm0();
        *(short8*)&hbuf[(r0 + 0) * LSTR + lane * 8] = hv0;
        *(short8*)&hbuf[(r0 + 1) * LSTR + lane * 8] = hv1;
        *(short8*)&hbuf[(r0 + 2) * LSTR + lane * 8] = hv2;
        *(short8*)&hbuf[(r0 + 3) * LSTR + lane * 8] = hv3;
        {
            short* pd = &p2buf[(t + 1) & 1][0];
            *(short8*)&pd[(r0 + 0) * LSTR + lane * 8] = pv0;
            *(short8*)&pd[(r0 + 1) * LSTR + lane * 8] = pv1;
            *(short8*)&pd[(r0 + 2) * LSTR + lane * 8] = pv2;
            *(short8*)&pd[(r0 + 3) * LSTR + lane * 8] = pv3;
        }
        __syncthreads();   // (e) B1: hbuf/p2buf visible

        // ---- (f) Phase B: h(t-1) MFMAs ----
        {
            const short* hbp = &hbuf[mrow * LSTR + quad * 8];
            #pragma unroll
            for (int i = 0; i < 16; ++i) {
                short8 a = *(const short8*)(hbp + i * 32);
                accA[(18 + i) & 3] = __builtin_amdgcn_mfma_f32_16x16x32_bf16(a, wfA[18 + i], accA[(18 + i) & 3], 0, 0, 0);
                accB[(18 + i) & 3] = __builtin_amdgcn_mfma_f32_16x16x32_bf16(a, wfB[18 + i], accB[(18 + i) & 3], 0, 0, 0);
            }
        }
        {
            floatx4 sA = accA[0] + accA[1] + accA[2] + accA[3];
            floatx4 sB = accB[0] + accB[1] + accB[2] + accB[3];
            #pragma unroll
            for (int r = 0; r < 4; ++r) {
                gsm[w][quad * 4 + r][mrow]      = sA[r] + biasA;
                gsm[w][quad * 4 + r][16 + mrow] = sB[r] + biasB;
            }
        }
        __syncthreads();   // (g) B2: gsm visible to cell waves

        // ---- (h) cell phase: waves 0,1 (4 cells/lane); producer signal path ----
        if (w < 2) {
            const int b16 = 8 * w + (lane >> 3);    // batch in 16
            const int cj  = (lane & 7) * 4;         // first cell of 4 (in 32)
            floatx4 gi = *(const floatx4*)&gsm[0][b16][cj];
            floatx4 gf = *(const floatx4*)&gsm[1][b16][cj];
            floatx4 gg = *(const floatx4*)&gsm[2][b16][cj];
            floatx4 go = *(const floatx4*)&gsm[3][b16][cj];
            union { unsigned long long u; unsigned short sh[4]; } hp;
            floatx4 hh;
            #pragma unroll
            for (int k = 0; k < 4; ++k) {
                float c = fsig(gf[k]) * cst[k] + fsig(gi[k]) * ftanh(gg[k]);
                cst[k] = c;
                float h = fsig(go[k]) * ftanh(c);
                hh[k] = h;
                union { bf16 b; unsigned short u; } cv;
                cv.b = __float2bfloat16(h);
                hp.sh[k] = cv.u;
            }
            short* hst = (short*)ring + ((size_t)(((t + 32) & 63) * 64 + bg * 16 + b16)) * 512
                         + wgc * 32 + cj;
            __hip_atomic_store((unsigned long long*)hst, hp.u, __ATOMIC_RELAXED, __HIP_MEMORY_SCOPE_AGENT);
            // wave-local ack of this wave's h stores, then its own flag.
            asm volatile("s_waitcnt vmcnt(0)" ::: "memory");
            __builtin_amdgcn_sched_barrier(0);
            if (lane == 0)
                __hip_atomic_store(gflags + (wgc * 2 + w) * 2, (unsigned)(t + 1),
                                   __ATOMIC_RELAXED, __HIP_MEMORY_SCOPE_AGENT);
            // out store after the flag so the next ack never waits on it.
            *(floatx4*)(out + (size_t)(bg * 16 + b16) * TT * 512 + (size_t)t * 512 + wgc * 32 + cj) = hh;
        }
        // no trailing barrier: waves 2,3 run ahead into (a0)/(a)/(b) of t+1.
    }
}

extern "C" void kernel_launch(void* const* d_in, const int* in_sizes, int n_in,
                              void* d_out, int out_size, void* d_ws, size_t ws_size,
                              hipStream_t stream) {
    const float* batch = (const float*)d_in[0];
    const float* Wih   = (const float*)d_in[1];
    const float* Whh   = (const float*)d_in[2];
    const float* bih   = (const float*)d_in[3];
    const float* bhh   = (const float*)d_in[4];
    float* out = (float*)d_out;

    char* p = (char*)d_ws;
    bf16*  Wc     = (bf16*)p;     p += (size_t)2048 * KPAD * 2;          // 4,456,448
    float* bias   = (float*)p;    p += (size_t)2048 * 4;                 // 8,192
    bf16*  xs     = (bf16*)p;     p += (size_t)TT * 64 * 64 * 2;         // 8,388,608
    bf16*  ring   = (bf16*)p;     p += (size_t)64 * 64 * 512 * 2;        // 4,194,304
    unsigned* flg = (unsigned*)p; p += 1024;                             // 4 groups x 32 flags x 8B

    // zero ring slots 0..31 (prev2 for t<32, h(-1) at slot 31) and flags
    hipMemsetAsync(ring, 0, (size_t)32 * 64 * 512 * 2, stream);
    hipMemsetAsync(flg, 0, 1024, stream);

    prep_wb<<<(2048 * KPAD + 255) / 256, 256, 0, stream>>>(Wih, Whh, bih, bhh, Wc, bias);
    prep_x<<<(TT * 64 * 64) / 256, 256, 0, stream>>>(batch, xs);

    lstm_persist<<<64, 256, 0, stream>>>(Wc, bias, xs, ring, out, flg);
}